// Round 1
// 548.283 us; speedup vs baseline: 1.0141x; 1.0141x over previous
//
#include <hip/hip_runtime.h>

// BatchedHGNNLayer: out = [Dv^-1/2 H De^-1 H^T Dv^-1/2 x] W^T + b
// B=8, N=4096, E=2048, C=128.
// R4: GEMM latency-hiding pass.
//   - gemm1_tr / gemm_bt_splitk4: double-buffered LDS, T3 minimum-2-phase
//     (stage tile kt+1 -> compute tile kt -> ONE barrier). Staging latency
//     hides under ds_read+MFMA instead of being drained cold at a barrier.
//   - Bijective XCD swizzle on both GEMM grids: lin%8 -> contiguous chunk,
//     so each XCD owns one batch. xsT[b] (1MiB) / out2T[b] (512KiB) become
//     L2-resident per XCD instead of being fetched by up to 8 XCDs.
//   k1 / st0 / st1 / k5 unchanged from R3.
// ws: Hbf 128MiB | xsT 8MiB | out2T 4MiB | P 32MiB | Q123 48MiB | Dv | De

#define EPS 1e-6f
constexpr int B_ = 8, N_ = 4096, E_ = 2048, C_ = 128;

typedef __bf16 bf16x8 __attribute__((ext_vector_type(8)));
typedef float f32x4 __attribute__((ext_vector_type(4)));

__device__ __forceinline__ unsigned int f2bf_pack(float lo, float hi) {
  unsigned int ul = __float_as_uint(lo), uh = __float_as_uint(hi);
  ul = (ul + 0x7fffu + ((ul >> 16) & 1u)) >> 16;
  uh = (uh + 0x7fffu + ((uh >> 16) & 1u)) & 0xffff0000u;
  return uh | ul;
}

__device__ __forceinline__ void gl2lds16(const void* g, void* l) {
  __builtin_amdgcn_global_load_lds(
      (const __attribute__((address_space(1))) void*)g,
      (__attribute__((address_space(3))) void*)l, 16, 0, 0);
}

// ---------------------------------------------------------------------------
// K1: stream H fp32 -> Hbf bf16, Dv row sums (plain stores), De col sums
// (register partials -> LDS cross-wave -> global atomics).
__global__ __launch_bounds__(256) void k1_fused(
    const float* __restrict__ H, unsigned short* __restrict__ Hbf,
    float* __restrict__ Dv, float* __restrict__ De) {
  __shared__ float Lde[4][2048];
  const int t = threadIdx.x;
  const int w = t >> 6, l = t & 63;
  const size_t row0 = (size_t)blockIdx.x * 64;
  const int b = (int)(row0 >> 12);  // N_ = 4096
  f32x4 dc[8];
#pragma unroll
  for (int j = 0; j < 8; ++j) dc[j] = (f32x4){0.f, 0.f, 0.f, 0.f};
  for (int i = 0; i < 16; ++i) {
    const size_t r = row0 + w * 16 + i;
    const float* src = H + r * E_;
    unsigned short* dst = Hbf + r * E_;
    float rs = 0.f;
#pragma unroll
    for (int j = 0; j < 8; ++j) {
      const f32x4 v = *(const f32x4*)(src + 256 * j + 4 * l);
      dc[j] += v;
      rs += v[0] + v[1] + v[2] + v[3];
      uint2 p;
      p.x = f2bf_pack(v[0], v[1]);
      p.y = f2bf_pack(v[2], v[3]);
      *(uint2*)(dst + 256 * j + 4 * l) = p;
    }
#pragma unroll
    for (int o = 32; o; o >>= 1) rs += __shfl_xor(rs, o);
    if (l == 0) Dv[r] = rs;
  }
#pragma unroll
  for (int j = 0; j < 8; ++j) *(f32x4*)&Lde[w][256 * j + 4 * l] = dc[j];
  __syncthreads();
  const int c0 = t * 8;
  f32x4 s0 = (f32x4){0.f, 0.f, 0.f, 0.f}, s1 = s0;
#pragma unroll
  for (int ww = 0; ww < 4; ++ww) {
    s0 += *(const f32x4*)&Lde[ww][c0];
    s1 += *(const f32x4*)&Lde[ww][c0 + 4];
  }
  float* dp = De + b * E_ + c0;
#pragma unroll
  for (int j = 0; j < 4; ++j) atomicAdd(dp + j, s0[j]);
#pragma unroll
  for (int j = 0; j < 4; ++j) atomicAdd(dp + 4 + j, s1[j]);
}

// ---------------------------------------------------------------------------
// st0: xsT[c][n] = bf16(x[n][c] * rsqrt(Dv+eps)). grid (N/128, B).
__global__ __launch_bounds__(256) void st0_scale_transpose(
    const float* __restrict__ in, const float* __restrict__ deg,
    unsigned short* __restrict__ outT) {
  __shared__ unsigned int T[128][66];
  const int t = threadIdx.x;
  in += (size_t)blockIdx.y * N_ * 128;
  outT += (size_t)blockIdx.y * 128 * N_;
  deg += (size_t)blockIdx.y * N_;
  const int r0 = blockIdx.x * 128;
  const int q = t >> 2, cq = t & 3;
  const float* row0 = in + (size_t)(r0 + 2 * q) * 128;
  const float* row1 = row0 + 128;
  const float s0 = 1.f / sqrtf(deg[r0 + 2 * q] + EPS);
  const float s1 = 1.f / sqrtf(deg[r0 + 2 * q + 1] + EPS);
#pragma unroll
  for (int i = 0; i < 8; ++i) {
    const int c = 16 * i + 4 * cq;
    const f32x4 a = *(const f32x4*)(row0 + c);
    const f32x4 b2 = *(const f32x4*)(row1 + c);
#pragma unroll
    for (int j = 0; j < 4; ++j) T[c + j][q] = f2bf_pack(a[j] * s0, b2[j] * s1);
  }
  __syncthreads();
  const int crow = t >> 1, h = t & 1;
  unsigned int u[32];
#pragma unroll
  for (int i = 0; i < 32; ++i) u[i] = T[crow][h * 32 + i];
  uint4* dst = (uint4*)(outT + (size_t)crow * N_ + r0 + 64 * h);
#pragma unroll
  for (int i = 0; i < 8; ++i)
    dst[i] = make_uint4(u[4 * i], u[4 * i + 1], u[4 * i + 2], u[4 * i + 3]);
}

// ---------------------------------------------------------------------------
// gemm1: P_sk[b][c][e] = sum_{n in split} xsT[c][n] * Hbf[n][e].
// A = xsT (k-fast, gl2lds, double-buffered). B = Hbf (k-MAJOR) transposed
// into LDS via packed ds_write_b32 with XOR swizzle, pipelined one tile
// ahead (regs hold tile kt+1, global prefetch is tile kt+2).
// One barrier per k-step. grid (E/128, 4, B) with bijective XCD remap.
__global__ __launch_bounds__(256) void gemm1_tr(
    const unsigned short* __restrict__ Hbf, const unsigned short* __restrict__ xsT,
    float* __restrict__ P) {
  __shared__ unsigned short Als[2][128 * 32];
  __shared__ unsigned short Bls[2][128 * 40];  // [e][n'], n' = n ^ 8*(q&3)
  const int t = threadIdx.x;
  const int w = t >> 6, l = t & 63;
  // XCD swizzle: lin -> contiguous chunk per XCD; chunk = one full batch.
  const int lin = blockIdx.x + 16 * blockIdx.y + 64 * blockIdx.z;  // [0,512)
  const int wg = (lin & 7) * 64 + (lin >> 3);
  const int et = wg & 15, sk = (wg >> 4) & 3, b = wg >> 6;
  const int k0 = sk * (N_ / 4);
  const int e0 = et * 128;
  const unsigned short* Ab = xsT + (size_t)b * C_ * N_ + k0;
  const int srow = l >> 2, scol = (l & 3) * 8;
  const unsigned short* ga0 = Ab + (size_t)(w * 32 + srow) * N_ + scol;
  const unsigned short* ga1 = ga0 + (size_t)16 * N_;
  const int la_off0 = (w * 32) * 32;
  const int la_off1 = (w * 32 + 16) * 32;
  const int np = t >> 4, q = t & 15;
  const int sw = (q & 3) << 3;
  const unsigned short* gb =
      Hbf + (size_t)b * N_ * E_ + (size_t)(k0 + 2 * np) * E_ + e0 + 8 * q;
  const int mrow = (w & 1) * 64, ncol = (w >> 1) * 64;
  const int fr = l & 15, fq = l >> 4;
  f32x4 acc[4][4];
#pragma unroll
  for (int i = 0; i < 4; ++i)
#pragma unroll
    for (int j = 0; j < 4; ++j) acc[i][j] = (f32x4){0.f, 0.f, 0.f, 0.f};
  const int nsteps = (N_ / 4) / 32;  // 32

  // Prologue: stage tile 0 into buf 0; prefetch B regs for tile 1.
  uint4 pl = *(const uint4*)gb;
  uint4 ph = *(const uint4*)(gb + E_);
  gl2lds16(ga0, &Als[0][la_off0]);
  gl2lds16(ga1, &Als[0][la_off1]);
  ga0 += 32;
  ga1 += 32;
  {
    unsigned int wl[4] = {pl.x, pl.y, pl.z, pl.w};
    unsigned int wh[4] = {ph.x, ph.y, ph.z, ph.w};
#pragma unroll
    for (int j = 0; j < 8; ++j) {
      const unsigned int lo16 = (wl[j >> 1] >> (16 * (j & 1))) & 0xffffu;
      const unsigned int hi16 = (wh[j >> 1] >> (16 * (j & 1))) & 0xffffu;
      *(unsigned int*)(&Bls[0][(8 * q + j) * 40 + ((2 * np) ^ sw)]) =
          lo16 | (hi16 << 16);
    }
  }
  pl = *(const uint4*)(gb + (size_t)32 * E_);
  ph = *(const uint4*)(gb + (size_t)33 * E_);
  __syncthreads();

  for (int kt = 0; kt < nsteps; ++kt) {
    const int cur = kt & 1, nxt = cur ^ 1;
    if (kt + 1 < nsteps) {
      gl2lds16(ga0, &Als[nxt][la_off0]);
      gl2lds16(ga1, &Als[nxt][la_off1]);
      ga0 += 32;
      ga1 += 32;
    }
    bf16x8 af[4], bfr[4];
#pragma unroll
    for (int i = 0; i < 4; ++i) {
      af[i] = *(const bf16x8*)(&Als[cur][(mrow + i * 16 + fr) * 32 + fq * 8]);
      const int brow = ncol + i * 16 + fr;
      const int nsw = (fq * 8) ^ (((brow >> 3) & 3) << 3);
      bfr[i] = *(const bf16x8*)(&Bls[cur][brow * 40 + nsw]);
    }
#pragma unroll
    for (int i = 0; i < 4; ++i)
#pragma unroll
      for (int j = 0; j < 4; ++j)
        acc[i][j] = __builtin_amdgcn_mfma_f32_16x16x32_bf16(af[i], bfr[j],
                                                            acc[i][j], 0, 0, 0);
    if (kt + 1 < nsteps) {
      // Write B tile kt+1 (held in pl/ph) into Bls[nxt].
      unsigned int wl[4] = {pl.x, pl.y, pl.z, pl.w};
      unsigned int wh[4] = {ph.x, ph.y, ph.z, ph.w};
#pragma unroll
      for (int j = 0; j < 8; ++j) {
        const unsigned int lo16 = (wl[j >> 1] >> (16 * (j & 1))) & 0xffffu;
        const unsigned int hi16 = (wh[j >> 1] >> (16 * (j & 1))) & 0xffffu;
        *(unsigned int*)(&Bls[nxt][(8 * q + j) * 40 + ((2 * np) ^ sw)]) =
            lo16 | (hi16 << 16);
      }
      if (kt + 2 < nsteps) {
        const unsigned short* g2 = gb + (size_t)(kt + 2) * 32 * E_;
        pl = *(const uint4*)g2;
        ph = *(const uint4*)(g2 + E_);
      }
    }
    __syncthreads();
  }
  float* Pb = P + (((size_t)sk * B_ + b) * C_) * E_ + e0;
#pragma unroll
  for (int i = 0; i < 4; ++i)
#pragma unroll
    for (int j = 0; j < 4; ++j)
#pragma unroll
      for (int r = 0; r < 4; ++r) {
        const int row = mrow + i * 16 + fq * 4 + r;  // C/D: col=lane&15, row=quad*4+reg
        const int col = ncol + j * 16 + fr;
        Pb[(size_t)row * E_ + col] = acc[i][j][r];
      }
}

// ---------------------------------------------------------------------------
// st1_sum4: out2T[b][c][e] = bf16(sum_s P_s[b][c][e] / (De[b][e]+eps)). Streaming.
__global__ __launch_bounds__(256) void st1_sum4(
    const float* __restrict__ P, const float* __restrict__ De,
    unsigned short* __restrict__ out2T) {
  const size_t SP = (size_t)B_ * C_ * E_;
  const size_t idx = ((size_t)blockIdx.x * 256 + threadIdx.x) * 8;
  const int e = (int)(idx & (E_ - 1));
  const int b = (int)(idx >> 18);  // C_*E_ = 2^18
  f32x4 s0 = (f32x4){0.f, 0.f, 0.f, 0.f}, s1 = s0;
#pragma unroll
  for (int s = 0; s < 4; ++s) {
    s0 += *(const f32x4*)(P + s * SP + idx);
    s1 += *(const f32x4*)(P + s * SP + idx + 4);
  }
  const f32x4 d0 = *(const f32x4*)(De + b * E_ + e);
  const f32x4 d1 = *(const f32x4*)(De + b * E_ + e + 4);
  uint4 o;
  o.x = f2bf_pack(s0[0] / (d0[0] + EPS), s0[1] / (d0[1] + EPS));
  o.y = f2bf_pack(s0[2] / (d0[2] + EPS), s0[3] / (d0[3] + EPS));
  o.z = f2bf_pack(s1[0] / (d1[0] + EPS), s1[1] / (d1[1] + EPS));
  o.w = f2bf_pack(s1[2] / (d1[2] + EPS), s1[3] / (d1[3] + EPS));
  *(uint4*)(out2T + idx) = o;
}

// ---------------------------------------------------------------------------
// gemm2: Q_sk[b][n][c] = sum_{e in split} Hbf[n][e] * out2T[c][e]. Both k-fast.
// Double-buffered LDS (stage kt+1 -> compute kt -> one barrier), bijective
// XCD remap (one batch per XCD -> out2T[b] L2-resident). grid (N/128, 4, B).
__global__ __launch_bounds__(256) void gemm_bt_splitk4(
    const unsigned short* __restrict__ A, const unsigned short* __restrict__ Bt,
    float* __restrict__ Q0, float* __restrict__ Q1, float* __restrict__ Q2,
    float* __restrict__ Q3, int M, int Kfull, int Kper) {
  __shared__ unsigned short Als[2][128 * 32];
  __shared__ unsigned short Bls[2][128 * 32];
  const int t = threadIdx.x;
  const int w = t >> 6, l = t & 63;
  const int lin = blockIdx.x + 32 * blockIdx.y + 128 * blockIdx.z;  // [0,1024)
  const int wg = (lin & 7) * 128 + (lin >> 3);
  const int mt = wg & 31, sk = (wg >> 5) & 3, b = wg >> 7;
  const unsigned short* Ab = A + ((size_t)b * M + mt * 128) * Kfull + (size_t)sk * Kper;
  const unsigned short* Btb = Bt + (size_t)b * 128 * Kfull + (size_t)sk * Kper;
  const int srow = l >> 2, scol = (l & 3) * 8;
  const unsigned short* ga0 = Ab + (size_t)(w * 32 + srow) * Kfull + scol;
  const unsigned short* ga1 = ga0 + (size_t)16 * Kfull;
  const unsigned short* gb0 = Btb + (size_t)(w * 32 + srow) * Kfull + scol;
  const unsigned short* gb1 = gb0 + (size_t)16 * Kfull;
  const int loff0 = (w * 32) * 32;
  const int loff1 = (w * 32 + 16) * 32;
  const int mrow = (w & 1) * 64, ncol = (w >> 1) * 64;
  const int fr = l & 15, fq = l >> 4;
  f32x4 acc[4][4];
#pragma unroll
  for (int i = 0; i < 4; ++i)
#pragma unroll
    for (int j = 0; j < 4; ++j) acc[i][j] = (f32x4){0.f, 0.f, 0.f, 0.f};
  const int nsteps = Kper / 32;

  // Prologue: stage tile 0 into buf 0.
  gl2lds16(ga0, &Als[0][loff0]);
  gl2lds16(ga1, &Als[0][loff1]);
  gl2lds16(gb0, &Bls[0][loff0]);
  gl2lds16(gb1, &Bls[0][loff1]);
  ga0 += 32; ga1 += 32; gb0 += 32; gb1 += 32;
  __syncthreads();

  for (int kt = 0; kt < nsteps; ++kt) {
    const int cur = kt & 1, nxt = cur ^ 1;
    if (kt + 1 < nsteps) {
      gl2lds16(ga0, &Als[nxt][loff0]);
      gl2lds16(ga1, &Als[nxt][loff1]);
      gl2lds16(gb0, &Bls[nxt][loff0]);
      gl2lds16(gb1, &Bls[nxt][loff1]);
      ga0 += 32; ga1 += 32; gb0 += 32; gb1 += 32;
    }
    bf16x8 af[4], bfr[4];
#pragma unroll
    for (int i = 0; i < 4; ++i) {
      af[i] = *(const bf16x8*)(&Als[cur][(mrow + i * 16 + fr) * 32 + fq * 8]);
      bfr[i] = *(const bf16x8*)(&Bls[cur][(ncol + i * 16 + fr) * 32 + fq * 8]);
    }
#pragma unroll
    for (int i = 0; i < 4; ++i)
#pragma unroll
      for (int j = 0; j < 4; ++j)
        acc[i][j] = __builtin_amdgcn_mfma_f32_16x16x32_bf16(af[i], bfr[j],
                                                            acc[i][j], 0, 0, 0);
    __syncthreads();
  }
  float* Q = (sk == 0) ? Q0 : (sk == 1) ? Q1 : (sk == 2) ? Q2 : Q3;
  float* Cb = Q + ((size_t)b * M + mt * 128) * 128;
#pragma unroll
  for (int i = 0; i < 4; ++i)
#pragma unroll
    for (int j = 0; j < 4; ++j)
#pragma unroll
      for (int r = 0; r < 4; ++r) {
        const int row = mrow + i * 16 + fq * 4 + r;
        const int col = ncol + j * 16 + fr;
        Cb[(size_t)row * 128 + col] = acc[i][j][r];
      }
}

// ---------------------------------------------------------------------------
// K5: out = bf16(sum_s Q_s * rsqrt(Dv)) @ W^T + b, in-place on Q0(=d_out).
__global__ __launch_bounds__(256) void k5_linear4(
    float* __restrict__ io, const float* __restrict__ q1,
    const float* __restrict__ q2, const float* __restrict__ q3,
    const float* __restrict__ W, const float* __restrict__ bias,
    const float* __restrict__ Dv) {
  __shared__ unsigned short Als[128 * 136];
  __shared__ unsigned short Wls[128 * 136];
  const int t = threadIdx.x;
  const size_t r0 = (size_t)blockIdx.x * 128;
  {
    const int row = t >> 1, h = t & 1;
    const size_t off = (r0 + row) * 128 + h * 64;
    const float sc = 1.f / sqrtf(Dv[r0 + row] + EPS);
    unsigned short* ld = Als + row * 136 + h * 64;
    const float* wsrc = W + row * 128 + h * 64;
    unsigned short* lw = Wls + row * 136 + h * 64;
#pragma unroll
    for (int i = 0; i < 16; ++i) {
      f32x4 a = *(const f32x4*)(io + off + 4 * i);
      a += *(const f32x4*)(q1 + off + 4 * i);
      a += *(const f32x4*)(q2 + off + 4 * i);
      a += *(const f32x4*)(q3 + off + 4 * i);
      uint2 p;
      p.x = f2bf_pack(a[0] * sc, a[1] * sc);
      p.y = f2bf_pack(a[2] * sc, a[3] * sc);
      *(uint2*)(ld + 4 * i) = p;
      const f32x4 ww = *(const f32x4*)(wsrc + 4 * i);
      uint2 pw;
      pw.x = f2bf_pack(ww[0], ww[1]);
      pw.y = f2bf_pack(ww[2], ww[3]);
      *(uint2*)(lw + 4 * i) = pw;
    }
  }
  __syncthreads();
  const int w = t >> 6, l = t & 63;
  const int mrow = (w & 1) * 64, ncol = (w >> 1) * 64;
  const int fr = l & 15, fq = l >> 4;
  f32x4 acc[4][4];
#pragma unroll
  for (int i = 0; i < 4; ++i)
#pragma unroll
    for (int j = 0; j < 4; ++j) acc[i][j] = (f32x4){0.f, 0.f, 0.f, 0.f};
#pragma unroll
  for (int s = 0; s < 4; ++s) {
    bf16x8 af[4], bfr[4];
#pragma unroll
    for (int i = 0; i < 4; ++i) {
      af[i] = *(const bf16x8*)(Als + (mrow + i * 16 + fr) * 136 + s * 32 + fq * 8);
      bfr[i] = *(const bf16x8*)(Wls + (ncol + i * 16 + fr) * 136 + s * 32 + fq * 8);
    }
#pragma unroll
    for (int i = 0; i < 4; ++i)
#pragma unroll
      for (int j = 0; j < 4; ++j)
        acc[i][j] = __builtin_amdgcn_mfma_f32_16x16x32_bf16(af[i], bfr[j], acc[i][j], 0, 0, 0);
  }
#pragma unroll
  for (int i = 0; i < 4; ++i)
#pragma unroll
    for (int j = 0; j < 4; ++j)
#pragma unroll
      for (int r = 0; r < 4; ++r) {
        const int row = mrow + i * 16 + fq * 4 + r;
        const int col = ncol + j * 16 + fr;
        io[(r0 + row) * 128 + col] = acc[i][j][r] + bias[col];
      }
}

// ---------------------------------------------------------------------------
extern "C" void kernel_launch(void* const* d_in, const int* in_sizes, int n_in,
                              void* d_out, int out_size, void* d_ws, size_t ws_size,
                              hipStream_t stream) {
  const float* x = (const float*)d_in[0];
  const float* H = (const float*)d_in[1];
  const float* W = (const float*)d_in[2];
  const float* bias = (const float*)d_in[3];
  float* out = (float*)d_out;

  unsigned short* Hbf = (unsigned short*)d_ws;          // [B][N][E] bf16, 128MiB
  unsigned short* xsT = Hbf + (size_t)B_ * N_ * E_;     // [B][C][N] bf16, 8MiB
  unsigned short* out2T = xsT + (size_t)B_ * C_ * N_;   // [B][C][E] bf16, 4MiB
  float* P = (float*)(out2T + (size_t)B_ * C_ * E_);    // [4][B][C][E] f32, 32MiB
  float* Q123 = P + 4 * (size_t)B_ * C_ * E_;           // [3][B][N][C] f32, 48MiB
  float* Dv = Q123 + 3 * (size_t)B_ * N_ * C_;          // [B][N]
  float* De = Dv + B_ * N_;                             // [B][E]

  float* q1 = Q123;
  float* q2 = Q123 + (size_t)B_ * N_ * C_;
  float* q3 = Q123 + 2 * (size_t)B_ * N_ * C_;

  hipMemsetAsync(De, 0, (size_t)B_ * E_ * sizeof(float), stream);

  k1_fused<<<dim3(B_ * N_ / 64), 256, 0, stream>>>(H, Hbf, Dv, De);
  st0_scale_transpose<<<dim3(N_ / 128, B_), 256, 0, stream>>>(x, Dv, xsT);
  gemm1_tr<<<dim3(E_ / 128, 4, B_), 256, 0, stream>>>(Hbf, xsT, P);
  st1_sum4<<<dim3(B_ * C_ * E_ / 8 / 256), 256, 0, stream>>>(P, De, out2T);
  gemm_bt_splitk4<<<dim3(N_ / 128, 4, B_), 256, 0, stream>>>(
      Hbf, out2T, out, q1, q2, q3, N_, E_, E_ / 4);
  k5_linear4<<<dim3(B_ * N_ / 128), 256, 0, stream>>>(out, q1, q2, q3, W, bias, Dv);
}

// Round 2
// 521.872 us; speedup vs baseline: 1.0654x; 1.0506x over previous
//
#include <hip/hip_runtime.h>

// BatchedHGNNLayer: out = [Dv^-1/2 H De^-1 H^T Dv^-1/2 x] W^T + b
// B=8, N=4096, E=2048, C=128.
// R5: never-drain pipelines + k5 fusion.
//   k0_prep: zero De + build pre-swizzled bf16 W (replaces memset).
//   k1_fused: H fp32 -> Hbf bf16 + Dv + De (unchanged).
//   st0: xsT[c][n] = bf16(x*rsqrt(Dv)) (unchanged).
//   gemm1_tr: 3-buffer LDS, raw s_barrier, counted s_waitcnt vmcnt(2),
//     clamped prefetch addresses -> loads never drained in the K-loop.
//   st1_sum4: P/De -> out2T bf16 (unchanged).
//   gemm2_fused: FULL-K (grid 256, one batch per XCD), same counted-vmcnt(4)
//     3-buffer pipeline, fused epilogue: scale rsqrt(Dv) -> bf16 -> XOR-swz
//     LDS -> MFMA vs pre-swizzled W -> +bias -> out. Q123 and k5 eliminated.
// ws: Hbf 128MiB | xsT 8MiB | out2T 4MiB | P 32MiB | Wsw 32KiB | Dv | De

#define EPS 1e-6f
constexpr int B_ = 8, N_ = 4096, E_ = 2048, C_ = 128;

typedef __bf16 bf16x8 __attribute__((ext_vector_type(8)));
typedef float f32x4 __attribute__((ext_vector_type(4)));

__device__ __forceinline__ unsigned int f2bf_pack(float lo, float hi) {
  unsigned int ul = __float_as_uint(lo), uh = __float_as_uint(hi);
  ul = (ul + 0x7fffu + ((ul >> 16) & 1u)) >> 16;
  uh = (uh + 0x7fffu + ((uh >> 16) & 1u)) & 0xffff0000u;
  return uh | ul;
}

__device__ __forceinline__ unsigned short f2bf1(float x) {
  unsigned int u = __float_as_uint(x);
  return (unsigned short)((u + 0x7fffu + ((u >> 16) & 1u)) >> 16);
}

__device__ __forceinline__ void gl2lds16(const void* g, void* l) {
  __builtin_amdgcn_global_load_lds(
      (const __attribute__((address_space(1))) void*)g,
      (__attribute__((address_space(3))) void*)l, 16, 0, 0);
}

// ---------------------------------------------------------------------------
// k0_prep: De = 0; Wsw[row][col ^ ((row&7)<<3)] = bf16(W[row][col]).
// grid 16 x 256; 4096 threads x 4 elems covers both 16K-float arrays.
__global__ __launch_bounds__(256) void k0_prep(
    const float* __restrict__ W, unsigned short* __restrict__ Wsw,
    float* __restrict__ De) {
  const int i4 = (blockIdx.x * 256 + threadIdx.x) * 4;
  *(f32x4*)(De + i4) = (f32x4){0.f, 0.f, 0.f, 0.f};
  const int row = i4 >> 7, col = i4 & 127;
  const f32x4 v = *(const f32x4*)(W + i4);
  uint2 p;
  p.x = f2bf_pack(v[0], v[1]);
  p.y = f2bf_pack(v[2], v[3]);
  *(uint2*)(Wsw + row * 128 + (col ^ ((row & 7) << 3))) = p;
}

// ---------------------------------------------------------------------------
// K1: stream H fp32 -> Hbf bf16, Dv row sums, De col sums (LDS + atomics).
__global__ __launch_bounds__(256) void k1_fused(
    const float* __restrict__ H, unsigned short* __restrict__ Hbf,
    float* __restrict__ Dv, float* __restrict__ De) {
  __shared__ float Lde[4][2048];
  const int t = threadIdx.x;
  const int w = t >> 6, l = t & 63;
  const size_t row0 = (size_t)blockIdx.x * 64;
  const int b = (int)(row0 >> 12);  // N_ = 4096
  f32x4 dc[8];
#pragma unroll
  for (int j = 0; j < 8; ++j) dc[j] = (f32x4){0.f, 0.f, 0.f, 0.f};
  for (int i = 0; i < 16; ++i) {
    const size_t r = row0 + w * 16 + i;
    const float* src = H + r * E_;
    unsigned short* dst = Hbf + r * E_;
    float rs = 0.f;
#pragma unroll
    for (int j = 0; j < 8; ++j) {
      const f32x4 v = *(const f32x4*)(src + 256 * j + 4 * l);
      dc[j] += v;
      rs += v[0] + v[1] + v[2] + v[3];
      uint2 p;
      p.x = f2bf_pack(v[0], v[1]);
      p.y = f2bf_pack(v[2], v[3]);
      *(uint2*)(dst + 256 * j + 4 * l) = p;
    }
#pragma unroll
    for (int o = 32; o; o >>= 1) rs += __shfl_xor(rs, o);
    if (l == 0) Dv[r] = rs;
  }
#pragma unroll
  for (int j = 0; j < 8; ++j) *(f32x4*)&Lde[w][256 * j + 4 * l] = dc[j];
  __syncthreads();
  const int c0 = t * 8;
  f32x4 s0 = (f32x4){0.f, 0.f, 0.f, 0.f}, s1 = s0;
#pragma unroll
  for (int ww = 0; ww < 4; ++ww) {
    s0 += *(const f32x4*)&Lde[ww][c0];
    s1 += *(const f32x4*)&Lde[ww][c0 + 4];
  }
  float* dp = De + b * E_ + c0;
#pragma unroll
  for (int j = 0; j < 4; ++j) atomicAdd(dp + j, s0[j]);
#pragma unroll
  for (int j = 0; j < 4; ++j) atomicAdd(dp + 4 + j, s1[j]);
}

// ---------------------------------------------------------------------------
// st0: xsT[c][n] = bf16(x[n][c] * rsqrt(Dv+eps)). grid (N/128, B).
__global__ __launch_bounds__(256) void st0_scale_transpose(
    const float* __restrict__ in, const float* __restrict__ deg,
    unsigned short* __restrict__ outT) {
  __shared__ unsigned int T[128][66];
  const int t = threadIdx.x;
  in += (size_t)blockIdx.y * N_ * 128;
  outT += (size_t)blockIdx.y * 128 * N_;
  deg += (size_t)blockIdx.y * N_;
  const int r0 = blockIdx.x * 128;
  const int q = t >> 2, cq = t & 3;
  const float* row0 = in + (size_t)(r0 + 2 * q) * 128;
  const float* row1 = row0 + 128;
  const float s0 = 1.f / sqrtf(deg[r0 + 2 * q] + EPS);
  const float s1 = 1.f / sqrtf(deg[r0 + 2 * q + 1] + EPS);
#pragma unroll
  for (int i = 0; i < 8; ++i) {
    const int c = 16 * i + 4 * cq;
    const f32x4 a = *(const f32x4*)(row0 + c);
    const f32x4 b2 = *(const f32x4*)(row1 + c);
#pragma unroll
    for (int j = 0; j < 4; ++j) T[c + j][q] = f2bf_pack(a[j] * s0, b2[j] * s1);
  }
  __syncthreads();
  const int crow = t >> 1, h = t & 1;
  unsigned int u[32];
#pragma unroll
  for (int i = 0; i < 32; ++i) u[i] = T[crow][h * 32 + i];
  uint4* dst = (uint4*)(outT + (size_t)crow * N_ + r0 + 64 * h);
#pragma unroll
  for (int i = 0; i < 8; ++i)
    dst[i] = make_uint4(u[4 * i], u[4 * i + 1], u[4 * i + 2], u[4 * i + 3]);
}

// ---------------------------------------------------------------------------
__device__ __forceinline__ void writeB(unsigned short* dst, uint4 PL, uint4 PH,
                                       int q, int bwo) {
  unsigned int wl[4] = {PL.x, PL.y, PL.z, PL.w};
  unsigned int wh[4] = {PH.x, PH.y, PH.z, PH.w};
#pragma unroll
  for (int j = 0; j < 8; ++j) {
    const unsigned int lo16 = (wl[j >> 1] >> (16 * (j & 1))) & 0xffffu;
    const unsigned int hi16 = (wh[j >> 1] >> (16 * (j & 1))) & 0xffffu;
    *(unsigned int*)(dst + (8 * q + j) * 40 + bwo) = lo16 | (hi16 << 16);
  }
}

// gemm1: P_sk[b][c][e] = sum_{n in split} xsT[c][n] * Hbf[n][e].
// 3-buffer pipeline, raw s_barrier, counted vmcnt(2), clamped prefetch.
// Per-iter vmem order: [B-regs(t+2) x2, A-gl2lds(t+2) x2] -> at loop top,
// waiting vmcnt(2) leaves only A(t+1) in flight; guarantees A(t) staged and
// B(t+1) regs arrived. grid (E/128, 4, B) with bijective XCD remap.
__global__ __launch_bounds__(256) void gemm1_tr(
    const unsigned short* __restrict__ Hbf, const unsigned short* __restrict__ xsT,
    float* __restrict__ P) {
  __shared__ unsigned short Als[3][128 * 32];
  __shared__ unsigned short Bls[3][128 * 40];
  const int t = threadIdx.x;
  const int w = t >> 6, l = t & 63;
  const int lin = blockIdx.x + 16 * blockIdx.y + 64 * blockIdx.z;  // [0,512)
  const int wg = (lin & 7) * 64 + (lin >> 3);
  const int et = wg & 15, sk = (wg >> 4) & 3, b = wg >> 6;
  const int k0 = sk * (N_ / 4);
  const int e0 = et * 128;
  const unsigned short* Ab = xsT + (size_t)b * C_ * N_ + k0;
  const int srow = l >> 2, scol = (l & 3) * 8;
  const unsigned short* ga0 = Ab + (size_t)(w * 32 + srow) * N_ + scol;
  const unsigned short* ga1 = ga0 + (size_t)16 * N_;
  const int la0 = (w * 32) * 32;       // wave-uniform LDS stage offsets
  const int la1 = (w * 32 + 16) * 32;
  const int np = t >> 4, q = t & 15;
  const int bwo = (2 * np) ^ ((q & 3) << 3);
  const unsigned short* gb =
      Hbf + (size_t)b * N_ * E_ + (size_t)(k0 + 2 * np) * E_ + e0 + 8 * q;
  const int mrow = (w & 1) * 64, ncol = (w >> 1) * 64;
  const int fr = l & 15, fq = l >> 4;
  f32x4 acc[4][4];
#pragma unroll
  for (int i = 0; i < 4; ++i)
#pragma unroll
    for (int j = 0; j < 4; ++j) acc[i][j] = (f32x4){0.f, 0.f, 0.f, 0.f};
  constexpr int nsteps = (N_ / 4) / 32;  // 32 (even)

  unsigned short *A0 = &Als[0][0], *A1 = &Als[1][0], *A2 = &Als[2][0];
  unsigned short *B0 = &Bls[0][0], *B1 = &Bls[1][0], *B2 = &Bls[2][0];

  // Prologue: [B(0) regs, A(0) lds, B(1) regs, A(1) lds]
  uint4 pl0 = *(const uint4*)gb;
  uint4 ph0 = *(const uint4*)(gb + E_);
  gl2lds16(ga0, A0 + la0);
  gl2lds16(ga1, A0 + la1);
  uint4 pl1 = *(const uint4*)(gb + (size_t)32 * E_);
  uint4 ph1 = *(const uint4*)(gb + (size_t)33 * E_);
  gl2lds16(ga0 + 32, A1 + la0);
  gl2lds16(ga1 + 32, A1 + la1);
  asm volatile("s_waitcnt vmcnt(6)" ::: "memory");  // B(0) regs arrived
  writeB(B0, pl0, ph0, q, bwo);

  for (int kt = 0; kt < nsteps; kt += 2) {
    // ---- even sub-iter: tile kt; write B(kt+1) from pl1; load B(kt+2)->pl0
    {
      asm volatile("s_waitcnt vmcnt(2) lgkmcnt(0)" ::: "memory");
      __builtin_amdgcn_s_barrier();
      asm volatile("" ::: "memory");
      writeB(B1, pl1, ph1, q, bwo);
      const int tc = (kt + 2 < nsteps) ? kt + 2 : nsteps - 1;
      const unsigned short* g2 = gb + (size_t)tc * 32 * E_;
      pl0 = *(const uint4*)g2;
      ph0 = *(const uint4*)(g2 + E_);
      gl2lds16(ga0 + tc * 32, A2 + la0);
      gl2lds16(ga1 + tc * 32, A2 + la1);
      bf16x8 af[4], bfr[4];
#pragma unroll
      for (int i = 0; i < 4; ++i) {
        af[i] = *(const bf16x8*)(A0 + (mrow + i * 16 + fr) * 32 + fq * 8);
        const int brow = ncol + i * 16 + fr;
        const int nsw = (fq * 8) ^ (((brow >> 3) & 3) << 3);
        bfr[i] = *(const bf16x8*)(B0 + brow * 40 + nsw);
      }
#pragma unroll
      for (int i = 0; i < 4; ++i)
#pragma unroll
        for (int j = 0; j < 4; ++j)
          acc[i][j] = __builtin_amdgcn_mfma_f32_16x16x32_bf16(af[i], bfr[j],
                                                              acc[i][j], 0, 0, 0);
      unsigned short* x0 = A0; A0 = A1; A1 = A2; A2 = x0;
      unsigned short* y0 = B0; B0 = B1; B1 = B2; B2 = y0;
    }
    // ---- odd sub-iter: tile kt+1; write B(kt+2) from pl0; load B(kt+3)->pl1
    {
      asm volatile("s_waitcnt vmcnt(2) lgkmcnt(0)" ::: "memory");
      __builtin_amdgcn_s_barrier();
      asm volatile("" ::: "memory");
      writeB(B1, pl0, ph0, q, bwo);
      const int tc = (kt + 3 < nsteps) ? kt + 3 : nsteps - 1;
      const unsigned short* g2 = gb + (size_t)tc * 32 * E_;
      pl1 = *(const uint4*)g2;
      ph1 = *(const uint4*)(g2 + E_);
      gl2lds16(ga0 + tc * 32, A2 + la0);
      gl2lds16(ga1 + tc * 32, A2 + la1);
      bf16x8 af[4], bfr[4];
#pragma unroll
      for (int i = 0; i < 4; ++i) {
        af[i] = *(const bf16x8*)(A0 + (mrow + i * 16 + fr) * 32 + fq * 8);
        const int brow = ncol + i * 16 + fr;
        const int nsw = (fq * 8) ^ (((brow >> 3) & 3) << 3);
        bfr[i] = *(const bf16x8*)(B0 + brow * 40 + nsw);
      }
#pragma unroll
      for (int i = 0; i < 4; ++i)
#pragma unroll
        for (int j = 0; j < 4; ++j)
          acc[i][j] = __builtin_amdgcn_mfma_f32_16x16x32_bf16(af[i], bfr[j],
                                                              acc[i][j], 0, 0, 0);
      unsigned short* x0 = A0; A0 = A1; A1 = A2; A2 = x0;
      unsigned short* y0 = B0; B0 = B1; B1 = B2; B2 = y0;
    }
  }
  // Drain in-flight gl2lds before workgroup can retire (LDS reuse hazard).
  asm volatile("s_waitcnt vmcnt(0) lgkmcnt(0)" ::: "memory");
  float* Pb = P + (((size_t)sk * B_ + b) * C_) * E_ + e0;
#pragma unroll
  for (int i = 0; i < 4; ++i)
#pragma unroll
    for (int j = 0; j < 4; ++j)
#pragma unroll
      for (int r = 0; r < 4; ++r) {
        const int row = mrow + i * 16 + fq * 4 + r;  // C/D: col=lane&15
        const int col = ncol + j * 16 + fr;
        Pb[(size_t)row * E_ + col] = acc[i][j][r];
      }
}

// ---------------------------------------------------------------------------
// st1_sum4: out2T[b][c][e] = bf16(sum_s P_s[b][c][e] / (De[b][e]+eps)).
__global__ __launch_bounds__(256) void st1_sum4(
    const float* __restrict__ P, const float* __restrict__ De,
    unsigned short* __restrict__ out2T) {
  const size_t SP = (size_t)B_ * C_ * E_;
  const size_t idx = ((size_t)blockIdx.x * 256 + threadIdx.x) * 8;
  const int e = (int)(idx & (E_ - 1));
  const int b = (int)(idx >> 18);  // C_*E_ = 2^18
  f32x4 s0 = (f32x4){0.f, 0.f, 0.f, 0.f}, s1 = s0;
#pragma unroll
  for (int s = 0; s < 4; ++s) {
    s0 += *(const f32x4*)(P + s * SP + idx);
    s1 += *(const f32x4*)(P + s * SP + idx + 4);
  }
  const f32x4 d0 = *(const f32x4*)(De + b * E_ + e);
  const f32x4 d1 = *(const f32x4*)(De + b * E_ + e + 4);
  uint4 o;
  o.x = f2bf_pack(s0[0] / (d0[0] + EPS), s0[1] / (d0[1] + EPS));
  o.y = f2bf_pack(s0[2] / (d0[2] + EPS), s0[3] / (d0[3] + EPS));
  o.z = f2bf_pack(s1[0] / (d1[0] + EPS), s1[1] / (d1[1] + EPS));
  o.w = f2bf_pack(s1[2] / (d1[2] + EPS), s1[3] / (d1[3] + EPS));
  *(uint4*)(out2T + idx) = o;
}

// ---------------------------------------------------------------------------
// gemm2_fused: Q[b][n][c] = sum_e Hbf[n][e]*out2T[c][e] (FULL K),
// then out = bf16(Q * rsqrt(Dv)) @ Wsw^T + bias, all in one kernel.
// grid (N/128, 1, B) = 256 blocks; XCD remap puts one batch per XCD.
// K-loop: 3-buffer, counted vmcnt(4), raw barriers, clamped prefetch.
// Epilogue LDS (64 KiB union with stage bufs): Xls[128][128] XOR-swizzled,
// Wls staged linearly from pre-swizzled Wsw.
__global__ __launch_bounds__(256) void gemm2_fused(
    const unsigned short* __restrict__ Hbf, const unsigned short* __restrict__ out2T,
    const unsigned short* __restrict__ Wsw, const float* __restrict__ bias,
    const float* __restrict__ Dv, float* __restrict__ out) {
  __shared__ unsigned short LDS[32768];  // 64 KiB
  const int t = threadIdx.x;
  const int w = t >> 6, l = t & 63;
  const int lin = blockIdx.x + 32 * blockIdx.z;  // [0,256)
  const int wg = (lin & 7) * 32 + (lin >> 3);
  const int mt = wg & 31, b = wg >> 5;
  const int n0 = mt * 128;
  const unsigned short* Ab = Hbf + ((size_t)b * N_ + n0) * E_;
  const unsigned short* Btb = out2T + (size_t)b * C_ * E_;
  const int srow = l >> 2, scol = (l & 3) * 8;
  const unsigned short* ga0 = Ab + (size_t)(w * 32 + srow) * E_ + scol;
  const unsigned short* ga1 = ga0 + (size_t)16 * E_;
  const unsigned short* gb0 = Btb + (size_t)(w * 32 + srow) * E_ + scol;
  const unsigned short* gb1 = gb0 + (size_t)16 * E_;
  const int la0 = (w * 32) * 32, la1 = (w * 32 + 16) * 32;  // wave-uniform
  unsigned short *A0 = LDS, *A1 = LDS + 4096, *A2 = LDS + 8192;
  unsigned short *B0 = LDS + 12288, *B1 = LDS + 16384, *B2 = LDS + 20480;
  const int mrow = (w & 1) * 64, ncol = (w >> 1) * 64;
  const int fr = l & 15, fq = l >> 4;
  f32x4 acc[4][4];
#pragma unroll
  for (int i = 0; i < 4; ++i)
#pragma unroll
    for (int j = 0; j < 4; ++j) acc[i][j] = (f32x4){0.f, 0.f, 0.f, 0.f};
  constexpr int nsteps = E_ / 32;  // 64

  // Prologue: stage tiles 0 and 1 (8 gl2lds outstanding).
  gl2lds16(ga0, A0 + la0); gl2lds16(ga1, A0 + la1);
  gl2lds16(gb0, B0 + la0); gl2lds16(gb1, B0 + la1);
  gl2lds16(ga0 + 32, A1 + la0); gl2lds16(ga1 + 32, A1 + la1);
  gl2lds16(gb0 + 32, B1 + la0); gl2lds16(gb1 + 32, B1 + la1);

  for (int kt = 0; kt < nsteps; ++kt) {
    asm volatile("s_waitcnt vmcnt(4)" ::: "memory");  // tile kt staged
    __builtin_amdgcn_s_barrier();
    asm volatile("" ::: "memory");
    const int tc = (kt + 2 < nsteps) ? kt + 2 : nsteps - 1;
    gl2lds16(ga0 + tc * 32, A2 + la0);
    gl2lds16(ga1 + tc * 32, A2 + la1);
    gl2lds16(gb0 + tc * 32, B2 + la0);
    gl2lds16(gb1 + tc * 32, B2 + la1);
    bf16x8 af[4], bfr[4];
#pragma unroll
    for (int i = 0; i < 4; ++i) {
      af[i] = *(const bf16x8*)(A0 + (mrow + i * 16 + fr) * 32 + fq * 8);
      bfr[i] = *(const bf16x8*)(B0 + (ncol + i * 16 + fr) * 32 + fq * 8);
    }
#pragma unroll
    for (int i = 0; i < 4; ++i)
#pragma unroll
      for (int j = 0; j < 4; ++j)
        acc[i][j] = __builtin_amdgcn_mfma_f32_16x16x32_bf16(af[i], bfr[j],
                                                            acc[i][j], 0, 0, 0);
    unsigned short* x0 = A0; A0 = A1; A1 = A2; A2 = x0;
    unsigned short* y0 = B0; B0 = B1; B1 = B2; B2 = y0;
  }

  // Drain all staging before reusing LDS for the epilogue.
  asm volatile("s_waitcnt vmcnt(0) lgkmcnt(0)" ::: "memory");
  __builtin_amdgcn_s_barrier();
  asm volatile("" ::: "memory");

  unsigned short* Xls = LDS;           // [128][128] XOR-swizzled, 32 KiB
  unsigned short* Wls = LDS + 16384;   // [128][128] pre-swizzled, 32 KiB
  // Stage Wsw -> Wls linearly (swizzle already baked into global layout).
  {
    const unsigned short* wgsrc = Wsw + w * 512 + l * 8;
    unsigned short* wldst = Wls + w * 512;  // wave-uniform
#pragma unroll
    for (int rr = 0; rr < 8; ++rr)
      gl2lds16(wgsrc + rr * 2048, wldst + rr * 2048);
  }
  // Scale, round to bf16, scatter into swizzled Xls.
  const float* Dvb = Dv + (size_t)b * N_ + n0;
  float sc[4][4];
#pragma unroll
  for (int i = 0; i < 4; ++i)
#pragma unroll
    for (int r = 0; r < 4; ++r)
      sc[i][r] = 1.f / sqrtf(Dvb[mrow + i * 16 + fq * 4 + r] + EPS);
#pragma unroll
  for (int i = 0; i < 4; ++i)
#pragma unroll
    for (int j = 0; j < 4; ++j)
#pragma unroll
      for (int r = 0; r < 4; ++r) {
        const int row = mrow + i * 16 + fq * 4 + r;
        const int col = ncol + j * 16 + fr;
        Xls[row * 128 + (col ^ ((row & 7) << 3))] = f2bf1(acc[i][j][r] * sc[i][r]);
      }
  asm volatile("s_waitcnt vmcnt(0) lgkmcnt(0)" ::: "memory");
  __builtin_amdgcn_s_barrier();
  asm volatile("" ::: "memory");
  // Second GEMM: out[n][co] = X[n][:] . W[co][:], K = 128 (4 steps).
  f32x4 a2[4][4];
#pragma unroll
  for (int i = 0; i < 4; ++i)
#pragma unroll
    for (int j = 0; j < 4; ++j) a2[i][j] = (f32x4){0.f, 0.f, 0.f, 0.f};
#pragma unroll
  for (int s = 0; s < 4; ++s) {
    bf16x8 af[4], bfr[4];
#pragma unroll
    for (int i = 0; i < 4; ++i) {
      const int xr = mrow + i * 16 + fr;
      af[i] = *(const bf16x8*)(Xls + xr * 128 + ((s * 32 + fq * 8) ^ ((xr & 7) << 3)));
      const int wr = ncol + i * 16 + fr;
      bfr[i] = *(const bf16x8*)(Wls + wr * 128 + ((s * 32 + fq * 8) ^ ((wr & 7) << 3)));
    }
#pragma unroll
    for (int i = 0; i < 4; ++i)
#pragma unroll
      for (int j = 0; j < 4; ++j)
        a2[i][j] = __builtin_amdgcn_mfma_f32_16x16x32_bf16(af[i], bfr[j],
                                                           a2[i][j], 0, 0, 0);
  }
  float* Ob = out + ((size_t)b * N_ + n0) * 128;
#pragma unroll
  for (int i = 0; i < 4; ++i)
#pragma unroll
    for (int j = 0; j < 4; ++j)
#pragma unroll
      for (int r = 0; r < 4; ++r) {
        const int row = mrow + i * 16 + fq * 4 + r;
        const int col = ncol + j * 16 + fr;
        Ob[(size_t)row * 128 + col] = a2[i][j][r] + bias[col];
      }
}

// ---------------------------------------------------------------------------
extern "C" void kernel_launch(void* const* d_in, const int* in_sizes, int n_in,
                              void* d_out, int out_size, void* d_ws, size_t ws_size,
                              hipStream_t stream) {
  const float* x = (const float*)d_in[0];
  const float* H = (const float*)d_in[1];
  const float* W = (const float*)d_in[2];
  const float* bias = (const float*)d_in[3];
  float* out = (float*)d_out;

  unsigned short* Hbf = (unsigned short*)d_ws;          // [B][N][E] bf16, 128MiB
  unsigned short* xsT = Hbf + (size_t)B_ * N_ * E_;     // [B][C][N] bf16, 8MiB
  unsigned short* out2T = xsT + (size_t)B_ * C_ * N_;   // [B][C][E] bf16, 4MiB
  float* P = (float*)(out2T + (size_t)B_ * C_ * E_);    // [4][B][C][E] f32, 32MiB
  unsigned short* Wsw = (unsigned short*)(P + 4 * (size_t)B_ * C_ * E_);  // 32KiB
  float* Dv = (float*)(Wsw + 128 * 128);                // [B][N]
  float* De = Dv + B_ * N_;                             // [B][E]

  k0_prep<<<dim3(16), 256, 0, stream>>>(W, Wsw, De);
  k1_fused<<<dim3(B_ * N_ / 64), 256, 0, stream>>>(H, Hbf, Dv, De);
  st0_scale_transpose<<<dim3(N_ / 128, B_), 256, 0, stream>>>(x, Dv, xsT);
  gemm1_tr<<<dim3(E_ / 128, 4, B_), 256, 0, stream>>>(Hbf, xsT, P);
  st1_sum4<<<dim3(B_ * C_ * E_ / 8 / 256), 256, 0, stream>>>(P, De, out2T);
  gemm2_fused<<<dim3(N_ / 128, 1, B_), 256, 0, stream>>>(Hbf, out2T, Wsw, bias,
                                                         Dv, out);
}

// Round 4
// 492.254 us; speedup vs baseline: 1.1295x; 1.0602x over previous
//
#include <hip/hip_runtime.h>

// BatchedHGNNLayer: out = [Dv^-1/2 H De^-1 H^T Dv^-1/2 x] W^T + b
// B=8, N=4096, E=2048, C=128.
// R7 (= R6 resubmit; previous bench died to container infra, kernel audited
// clean for races/deadlocks):
//   k0_prep: zero De + pre-swizzled bf16 W.
//   k1_fused: H fp32 -> Hbf bf16 + Dv + De  AND (merged st0) xsT =
//     bf16(x * rsqrt(Dv)) transposed, using the block-local Dv. -1 dispatch.
//   gemm1_tr: R5 structure (3-buf, counted vmcnt(2), XCD remap), 2 blk/CU.
//   st1_sum4: P/De -> out2T bf16.
//   gemm2_fused: M-tile 64 -> grid 512 = 2 blk/CU (was 1: 1 wave/SIMD, all
//     latency exposed). 3-buf counted vmcnt(3). Fused epilogue: rsqrt(Dv) ->
//     bf16 -> XOR-swz LDS -> MFMA vs Wsw -> +bias -> out.
// ws: Hbf 128MiB | xsT 8MiB | out2T 4MiB | P 32MiB | Wsw 32KiB | Dv | De

#define EPS 1e-6f
constexpr int B_ = 8, N_ = 4096, E_ = 2048, C_ = 128;

typedef __bf16 bf16x8 __attribute__((ext_vector_type(8)));
typedef float f32x4 __attribute__((ext_vector_type(4)));

__device__ __forceinline__ unsigned int f2bf_pack(float lo, float hi) {
  unsigned int ul = __float_as_uint(lo), uh = __float_as_uint(hi);
  ul = (ul + 0x7fffu + ((ul >> 16) & 1u)) >> 16;
  uh = (uh + 0x7fffu + ((uh >> 16) & 1u)) & 0xffff0000u;
  return uh | ul;
}

__device__ __forceinline__ unsigned short f2bf1(float x) {
  unsigned int u = __float_as_uint(x);
  return (unsigned short)((u + 0x7fffu + ((u >> 16) & 1u)) >> 16);
}

__device__ __forceinline__ void gl2lds16(const void* g, void* l) {
  __builtin_amdgcn_global_load_lds(
      (const __attribute__((address_space(1))) void*)g,
      (__attribute__((address_space(3))) void*)l, 16, 0, 0);
}

// ---------------------------------------------------------------------------
// k0_prep: De = 0; Wsw[row][col ^ ((row&7)<<3)] = bf16(W[row][col]).
__global__ __launch_bounds__(256) void k0_prep(
    const float* __restrict__ W, unsigned short* __restrict__ Wsw,
    float* __restrict__ De) {
  const int i4 = (blockIdx.x * 256 + threadIdx.x) * 4;
  *(f32x4*)(De + i4) = (f32x4){0.f, 0.f, 0.f, 0.f};
  const int row = i4 >> 7, col = i4 & 127;
  const f32x4 v = *(const f32x4*)(W + i4);
  uint2 p;
  p.x = f2bf_pack(v[0], v[1]);
  p.y = f2bf_pack(v[2], v[3]);
  *(uint2*)(Wsw + row * 128 + (col ^ ((row & 7) << 3))) = p;
}

// ---------------------------------------------------------------------------
// K1 (merged st0): per 64-row slab of one batch:
//   - stream H fp32 -> Hbf bf16; Dv row sums (global + Ldv); De col partials
//     (LDS cross-wave -> global atomics);
//   - load x rows, scale by rsqrt(Ldv), LDS-transpose, write xsT[c][n].
__global__ __launch_bounds__(256) void k1_fused(
    const float* __restrict__ H, const float* __restrict__ x,
    unsigned short* __restrict__ Hbf, unsigned short* __restrict__ xsT,
    float* __restrict__ Dv, float* __restrict__ De) {
  __shared__ float Lde[4][2048];
  __shared__ float Ldv[64];
  __shared__ unsigned int T[128][33];  // [col c][row pair], bf16-pair packed
  const int t = threadIdx.x;
  const int w = t >> 6, l = t & 63;
  const size_t row0 = (size_t)blockIdx.x * 64;
  const int b = (int)(row0 >> 12);  // N_ = 4096
  f32x4 dc[8];
#pragma unroll
  for (int j = 0; j < 8; ++j) dc[j] = (f32x4){0.f, 0.f, 0.f, 0.f};
  for (int i = 0; i < 16; ++i) {
    const size_t r = row0 + w * 16 + i;
    const float* src = H + r * E_;
    unsigned short* dst = Hbf + r * E_;
    float rs = 0.f;
#pragma unroll
    for (int j = 0; j < 8; ++j) {
      const f32x4 v = *(const f32x4*)(src + 256 * j + 4 * l);
      dc[j] += v;
      rs += v[0] + v[1] + v[2] + v[3];
      uint2 p;
      p.x = f2bf_pack(v[0], v[1]);
      p.y = f2bf_pack(v[2], v[3]);
      *(uint2*)(dst + 256 * j + 4 * l) = p;
    }
#pragma unroll
    for (int o = 32; o; o >>= 1) rs += __shfl_xor(rs, o);
    if (l == 0) {
      Dv[r] = rs;
      Ldv[w * 16 + i] = rs;
    }
  }
#pragma unroll
  for (int j = 0; j < 8; ++j) *(f32x4*)&Lde[w][256 * j + 4 * l] = dc[j];
  __syncthreads();
  // De reduction + atomics.
  {
    const int c0 = t * 8;
    f32x4 s0 = (f32x4){0.f, 0.f, 0.f, 0.f}, s1 = s0;
#pragma unroll
    for (int ww = 0; ww < 4; ++ww) {
      s0 += *(const f32x4*)&Lde[ww][c0];
      s1 += *(const f32x4*)&Lde[ww][c0 + 4];
    }
    float* dp = De + b * E_ + c0;
#pragma unroll
    for (int j = 0; j < 4; ++j) atomicAdd(dp + j, s0[j]);
#pragma unroll
    for (int j = 0; j < 4; ++j) atomicAdd(dp + 4 + j, s1[j]);
  }
  // Merged st0 phase 1: rows 2p,2p+1 scaled+packed into T[col][p].
  {
    const int p = t >> 3, cq = t & 7;
    const float s0 = 1.f / sqrtf(Ldv[2 * p] + EPS);
    const float s1 = 1.f / sqrtf(Ldv[2 * p + 1] + EPS);
    const float* r0p = x + (row0 + 2 * p) * 128;
    const float* r1p = r0p + 128;
#pragma unroll
    for (int i = 0; i < 4; ++i) {
      const int c = 32 * i + 4 * cq;
      const f32x4 a = *(const f32x4*)(r0p + c);
      const f32x4 b2 = *(const f32x4*)(r1p + c);
#pragma unroll
      for (int j = 0; j < 4; ++j) T[c + j][p] = f2bf_pack(a[j] * s0, b2[j] * s1);
    }
  }
  __syncthreads();
  // Phase 2: write xsT[c][n0..n0+63], 64B per thread.
  {
    const int crow = t >> 1, h = t & 1;
    const int nb = (int)(row0 & (N_ - 1));
    unsigned int u[16];
#pragma unroll
    for (int i = 0; i < 16; ++i) u[i] = T[crow][h * 16 + i];
    uint4* dst = (uint4*)(xsT + (size_t)b * C_ * N_ + (size_t)crow * N_ + nb + h * 32);
#pragma unroll
    for (int i = 0; i < 4; ++i)
      dst[i] = make_uint4(u[4 * i], u[4 * i + 1], u[4 * i + 2], u[4 * i + 3]);
  }
}

// ---------------------------------------------------------------------------
__device__ __forceinline__ void writeB(unsigned short* dst, uint4 PL, uint4 PH,
                                       int q, int bwo) {
  unsigned int wl[4] = {PL.x, PL.y, PL.z, PL.w};
  unsigned int wh[4] = {PH.x, PH.y, PH.z, PH.w};
#pragma unroll
  for (int j = 0; j < 8; ++j) {
    const unsigned int lo16 = (wl[j >> 1] >> (16 * (j & 1))) & 0xffffu;
    const unsigned int hi16 = (wh[j >> 1] >> (16 * (j & 1))) & 0xffffu;
    *(unsigned int*)(dst + (8 * q + j) * 40 + bwo) = lo16 | (hi16 << 16);
  }
}

// gemm1: P_sk[b][c][e] = sum_{n in split} xsT[c][n] * Hbf[n][e].
// 3-buffer pipeline, raw s_barrier, counted vmcnt(2), clamped prefetch.
__global__ __launch_bounds__(256) void gemm1_tr(
    const unsigned short* __restrict__ Hbf, const unsigned short* __restrict__ xsT,
    float* __restrict__ P) {
  __shared__ unsigned short Als[3][128 * 32];
  __shared__ unsigned short Bls[3][128 * 40];
  const int t = threadIdx.x;
  const int w = t >> 6, l = t & 63;
  const int lin = blockIdx.x + 16 * blockIdx.y + 64 * blockIdx.z;  // [0,512)
  const int wg = (lin & 7) * 64 + (lin >> 3);
  const int et = wg & 15, sk = (wg >> 4) & 3, b = wg >> 6;
  const int k0 = sk * (N_ / 4);
  const int e0 = et * 128;
  const unsigned short* Ab = xsT + (size_t)b * C_ * N_ + k0;
  const int srow = l >> 2, scol = (l & 3) * 8;
  const unsigned short* ga0 = Ab + (size_t)(w * 32 + srow) * N_ + scol;
  const unsigned short* ga1 = ga0 + (size_t)16 * N_;
  const int la0 = (w * 32) * 32;
  const int la1 = (w * 32 + 16) * 32;
  const int np = t >> 4, q = t & 15;
  const int bwo = (2 * np) ^ ((q & 3) << 3);
  const unsigned short* gb =
      Hbf + (size_t)b * N_ * E_ + (size_t)(k0 + 2 * np) * E_ + e0 + 8 * q;
  const int mrow = (w & 1) * 64, ncol = (w >> 1) * 64;
  const int fr = l & 15, fq = l >> 4;
  f32x4 acc[4][4];
#pragma unroll
  for (int i = 0; i < 4; ++i)
#pragma unroll
    for (int j = 0; j < 4; ++j) acc[i][j] = (f32x4){0.f, 0.f, 0.f, 0.f};
  constexpr int nsteps = (N_ / 4) / 32;  // 32 (even)

  unsigned short *A0 = &Als[0][0], *A1 = &Als[1][0], *A2 = &Als[2][0];
  unsigned short *B0 = &Bls[0][0], *B1 = &Bls[1][0], *B2 = &Bls[2][0];

  uint4 pl0 = *(const uint4*)gb;
  uint4 ph0 = *(const uint4*)(gb + E_);
  gl2lds16(ga0, A0 + la0);
  gl2lds16(ga1, A0 + la1);
  uint4 pl1 = *(const uint4*)(gb + (size_t)32 * E_);
  uint4 ph1 = *(const uint4*)(gb + (size_t)33 * E_);
  gl2lds16(ga0 + 32, A1 + la0);
  gl2lds16(ga1 + 32, A1 + la1);
  asm volatile("s_waitcnt vmcnt(6)" ::: "memory");
  writeB(B0, pl0, ph0, q, bwo);

  for (int kt = 0; kt < nsteps; kt += 2) {
    {
      asm volatile("s_waitcnt vmcnt(2) lgkmcnt(0)" ::: "memory");
      __builtin_amdgcn_s_barrier();
      asm volatile("" ::: "memory");
      writeB(B1, pl1, ph1, q, bwo);
      const int tc = (kt + 2 < nsteps) ? kt + 2 : nsteps - 1;
      const unsigned short* g2 = gb + (size_t)tc * 32 * E_;
      pl0 = *(const uint4*)g2;
      ph0 = *(const uint4*)(g2 + E_);
      gl2lds16(ga0 + tc * 32, A2 + la0);
      gl2lds16(ga1 + tc * 32, A2 + la1);
      bf16x8 af[4], bfr[4];
#pragma unroll
      for (int i = 0; i < 4; ++i) {
        af[i] = *(const bf16x8*)(A0 + (mrow + i * 16 + fr) * 32 + fq * 8);
        const int brow = ncol + i * 16 + fr;
        const int nsw = (fq * 8) ^ (((brow >> 3) & 3) << 3);
        bfr[i] = *(const bf16x8*)(B0 + brow * 40 + nsw);
      }
#pragma unroll
      for (int i = 0; i < 4; ++i)
#pragma unroll
        for (int j = 0; j < 4; ++j)
          acc[i][j] = __builtin_amdgcn_mfma_f32_16x16x32_bf16(af[i], bfr[j],
                                                              acc[i][j], 0, 0, 0);
      unsigned short* x0 = A0; A0 = A1; A1 = A2; A2 = x0;
      unsigned short* y0 = B0; B0 = B1; B1 = B2; B2 = y0;
    }
    {
      asm volatile("s_waitcnt vmcnt(2) lgkmcnt(0)" ::: "memory");
      __builtin_amdgcn_s_barrier();
      asm volatile("" ::: "memory");
      writeB(B1, pl0, ph0, q, bwo);
      const int tc = (kt + 3 < nsteps) ? kt + 3 : nsteps - 1;
      const unsigned short* g2 = gb + (size_t)tc * 32 * E_;
      pl1 = *(const uint4*)g2;
      ph1 = *(const uint4*)(g2 + E_);
      gl2lds16(ga0 + tc * 32, A2 + la0);
      gl2lds16(ga1 + tc * 32, A2 + la1);
      bf16x8 af[4], bfr[4];
#pragma unroll
      for (int i = 0; i < 4; ++i) {
        af[i] = *(const bf16x8*)(A0 + (mrow + i * 16 + fr) * 32 + fq * 8);
        const int brow = ncol + i * 16 + fr;
        const int nsw = (fq * 8) ^ (((brow >> 3) & 3) << 3);
        bfr[i] = *(const bf16x8*)(B0 + brow * 40 + nsw);
      }
#pragma unroll
      for (int i = 0; i < 4; ++i)
#pragma unroll
        for (int j = 0; j < 4; ++j)
          acc[i][j] = __builtin_amdgcn_mfma_f32_16x16x32_bf16(af[i], bfr[j],
                                                              acc[i][j], 0, 0, 0);
      unsigned short* x0 = A0; A0 = A1; A1 = A2; A2 = x0;
      unsigned short* y0 = B0; B0 = B1; B1 = B2; B2 = y0;
    }
  }
  asm volatile("s_waitcnt vmcnt(0) lgkmcnt(0)" ::: "memory");
  float* Pb = P + (((size_t)sk * B_ + b) * C_) * E_ + e0;
#pragma unroll
  for (int i = 0; i < 4; ++i)
#pragma unroll
    for (int j = 0; j < 4; ++j)
#pragma unroll
      for (int r = 0; r < 4; ++r) {
        const int row = mrow + i * 16 + fq * 4 + r;
        const int col = ncol + j * 16 + fr;
        Pb[(size_t)row * E_ + col] = acc[i][j][r];
      }
}

// ---------------------------------------------------------------------------
// st1_sum4: out2T[b][c][e] = bf16(sum_s P_s[b][c][e] / (De[b][e]+eps)).
__global__ __launch_bounds__(256) void st1_sum4(
    const float* __restrict__ P, const float* __restrict__ De,
    unsigned short* __restrict__ out2T) {
  const size_t SP = (size_t)B_ * C_ * E_;
  const size_t idx = ((size_t)blockIdx.x * 256 + threadIdx.x) * 8;
  const int e = (int)(idx & (E_ - 1));
  const int b = (int)(idx >> 18);  // C_*E_ = 2^18
  f32x4 s0 = (f32x4){0.f, 0.f, 0.f, 0.f}, s1 = s0;
#pragma unroll
  for (int s = 0; s < 4; ++s) {
    s0 += *(const f32x4*)(P + s * SP + idx);
    s1 += *(const f32x4*)(P + s * SP + idx + 4);
  }
  const f32x4 d0 = *(const f32x4*)(De + b * E_ + e);
  const f32x4 d1 = *(const f32x4*)(De + b * E_ + e + 4);
  uint4 o;
  o.x = f2bf_pack(s0[0] / (d0[0] + EPS), s0[1] / (d0[1] + EPS));
  o.y = f2bf_pack(s0[2] / (d0[2] + EPS), s0[3] / (d0[3] + EPS));
  o.z = f2bf_pack(s1[0] / (d1[0] + EPS), s1[1] / (d1[1] + EPS));
  o.w = f2bf_pack(s1[2] / (d1[2] + EPS), s1[3] / (d1[3] + EPS));
  *(uint4*)(out2T + idx) = o;
}

// ---------------------------------------------------------------------------
// gemm2_fused: Q[b][n][c] = sum_e Hbf[n][e]*out2T[c][e] (FULL K), M-tile 64,
// then out = bf16(Q * rsqrt(Dv)) @ Wsw^T + bias. grid (N/64, 1, B) = 512
// blocks (2/CU). 3-buffer, counted vmcnt(3). Waves split the C dimension.
__global__ __launch_bounds__(256) void gemm2_fused(
    const unsigned short* __restrict__ Hbf, const unsigned short* __restrict__ out2T,
    const unsigned short* __restrict__ Wsw, const float* __restrict__ bias,
    const float* __restrict__ Dv, float* __restrict__ out) {
  __shared__ unsigned short LDS[24576];  // 48 KiB
  const int t = threadIdx.x;
  const int w = t >> 6, l = t & 63;
  const int lin = blockIdx.x + 64 * blockIdx.z;  // [0,512)
  const int wg = (lin & 7) * 64 + (lin >> 3);
  const int mt = wg & 63, b = wg >> 6;
  const int n0 = mt * 64;
  const unsigned short* Ab = Hbf + ((size_t)b * N_ + n0) * E_;
  const unsigned short* Btb = out2T + (size_t)b * C_ * E_;
  const int srow = l >> 2, scol = (l & 3) * 8;
  // A: 64 rows, wave w stages rows w*16..w*16+15 (one gl2lds16/step).
  const unsigned short* ga0 = Ab + (size_t)(w * 16 + srow) * E_ + scol;
  // B: 128 rows, wave w stages rows w*32..w*32+31 (two gl2lds16/step).
  const unsigned short* gb0 = Btb + (size_t)(w * 32 + srow) * E_ + scol;
  const unsigned short* gb1 = gb0 + (size_t)16 * E_;
  const int la0 = w * 512;                       // A buf: 64*32 = 2048 ushort
  const int lb0 = w * 1024, lb1 = w * 1024 + 512;  // B buf: 128*32 = 4096
  unsigned short *A0 = LDS, *A1 = LDS + 2048, *A2 = LDS + 4096;
  unsigned short *B0 = LDS + 6144, *B1 = LDS + 10240, *B2 = LDS + 14336;
  const int ncol = w * 32;  // wave's 32-column C slice
  const int fr = l & 15, fq = l >> 4;
  f32x4 acc[4][2];
#pragma unroll
  for (int i = 0; i < 4; ++i)
#pragma unroll
    for (int j = 0; j < 2; ++j) acc[i][j] = (f32x4){0.f, 0.f, 0.f, 0.f};
  constexpr int nsteps = E_ / 32;  // 64

  // Prologue: stage tiles 0,1 (6 loads outstanding).
  gl2lds16(ga0, A0 + la0);
  gl2lds16(gb0, B0 + lb0); gl2lds16(gb1, B0 + lb1);
  gl2lds16(ga0 + 32, A1 + la0);
  gl2lds16(gb0 + 32, B1 + lb0); gl2lds16(gb1 + 32, B1 + lb1);

  for (int kt = 0; kt < nsteps; ++kt) {
    asm volatile("s_waitcnt vmcnt(3)" ::: "memory");  // tile kt staged
    __builtin_amdgcn_s_barrier();
    asm volatile("" ::: "memory");
    const int tc = (kt + 2 < nsteps) ? kt + 2 : nsteps - 1;
    gl2lds16(ga0 + tc * 32, A2 + la0);
    gl2lds16(gb0 + tc * 32, B2 + lb0);
    gl2lds16(gb1 + tc * 32, B2 + lb1);
    bf16x8 af[4], bfr[2];
#pragma unroll
    for (int i = 0; i < 4; ++i)
      af[i] = *(const bf16x8*)(A0 + (i * 16 + fr) * 32 + fq * 8);
#pragma unroll
    for (int j = 0; j < 2; ++j)
      bfr[j] = *(const bf16x8*)(B0 + (ncol + j * 16 + fr) * 32 + fq * 8);
#pragma unroll
    for (int i = 0; i < 4; ++i)
#pragma unroll
      for (int j = 0; j < 2; ++j)
        acc[i][j] = __builtin_amdgcn_mfma_f32_16x16x32_bf16(af[i], bfr[j],
                                                            acc[i][j], 0, 0, 0);
    unsigned short* x0 = A0; A0 = A1; A1 = A2; A2 = x0;
    unsigned short* y0 = B0; B0 = B1; B1 = B2; B2 = y0;
  }

  // Drain staging before LDS reuse.
  asm volatile("s_waitcnt vmcnt(0) lgkmcnt(0)" ::: "memory");
  __builtin_amdgcn_s_barrier();
  asm volatile("" ::: "memory");

  unsigned short* Xls = LDS;          // [64][128] XOR-swizzled, 16 KiB
  unsigned short* Wls = LDS + 8192;   // [128][128] pre-swizzled, 32 KiB
  // Stage Wsw -> Wls linearly (wave w: rows w*32..w*32+31 = 4096 ushorts).
  {
    const unsigned short* wgsrc = Wsw + w * 4096 + l * 8;
    unsigned short* wldst = Wls + w * 4096;
#pragma unroll
    for (int rr = 0; rr < 8; ++rr)
      gl2lds16(wgsrc + rr * 512, wldst + rr * 512);
  }
  // Scale by rsqrt(Dv), round to bf16, scatter into swizzled Xls.
  const float* Dvb = Dv + (size_t)b * N_ + n0;
  float sc[4][4];
#pragma unroll
  for (int i = 0; i < 4; ++i)
#pragma unroll
    for (int r = 0; r < 4; ++r)
      sc[i][r] = 1.f / sqrtf(Dvb[i * 16 + fq * 4 + r] + EPS);
#pragma unroll
  for (int i = 0; i < 4; ++i)
#pragma unroll
    for (int j = 0; j < 2; ++j)
#pragma unroll
      for (int r = 0; r < 4; ++r) {
        const int row = i * 16 + fq * 4 + r;
        const int col = ncol + j * 16 + fr;
        Xls[row * 128 + (col ^ ((row & 7) << 3))] = f2bf1(acc[i][j][r] * sc[i][r]);
      }
  asm volatile("s_waitcnt vmcnt(0) lgkmcnt(0)" ::: "memory");
  __builtin_amdgcn_s_barrier();
  asm volatile("" ::: "memory");
  // Second GEMM: out[n][co] = X[n][:] . W[co][:], K=128 (4 steps).
  f32x4 a2[4][2];
#pragma unroll
  for (int i = 0; i < 4; ++i)
#pragma unroll
    for (int j = 0; j < 2; ++j) a2[i][j] = (f32x4){0.f, 0.f, 0.f, 0.f};
#pragma unroll
  for (int s = 0; s < 4; ++s) {
    bf16x8 af[4], bfr[2];
#pragma unroll
    for (int i = 0; i < 4; ++i) {
      const int xr = i * 16 + fr;
      af[i] = *(const bf16x8*)(Xls + xr * 128 + ((s * 32 + fq * 8) ^ ((xr & 7) << 3)));
    }
#pragma unroll
    for (int j = 0; j < 2; ++j) {
      const int wr = ncol + j * 16 + fr;
      bfr[j] = *(const bf16x8*)(Wls + wr * 128 + ((s * 32 + fq * 8) ^ ((wr & 7) << 3)));
    }
#pragma unroll
    for (int i = 0; i < 4; ++i)
#pragma unroll
      for (int j = 0; j < 2; ++j)
        a2[i][j] = __builtin_amdgcn_mfma_f32_16x16x32_bf16(af[i], bfr[j],
                                                           a2[i][j], 0, 0, 0);
  }
  float* Ob = out + ((size_t)b * N_ + n0) * 128;
#pragma unroll
  for (int i = 0; i < 4; ++i)
#pragma unroll
    for (int j = 0; j < 2; ++j)
#pragma unroll
      for (int r = 0; r < 4; ++r) {
        const int row = i * 16 + fq * 4 + r;
        const int col = ncol + j * 16 + fr;
        Ob[(size_t)row * 128 + col] = a2[i][j][r] + bias[col];
      }
}

// ---------------------------------------------------------------------------
extern "C" void kernel_launch(void* const* d_in, const int* in_sizes, int n_in,
                              void* d_out, int out_size, void* d_ws, size_t ws_size,
                              hipStream_t stream) {
  const float* x = (const float*)d_in[0];
  const float* H = (const float*)d_in[1];
  const float* W = (const float*)d_in[2];
  const float* bias = (const float*)d_in[3];
  float* out = (float*)d_out;

  unsigned short* Hbf = (unsigned short*)d_ws;          // [B][N][E] bf16, 128MiB
  unsigned short* xsT = Hbf + (size_t)B_ * N_ * E_;     // [B][C][N] bf16, 8MiB
  unsigned short* out2T = xsT + (size_t)B_ * C_ * N_;   // [B][C][E] bf16, 4MiB
  float* P = (float*)(out2T + (size_t)B_ * C_ * E_);    // [4][B][C][E] f32, 32MiB
  unsigned short* Wsw = (unsigned short*)(P + 4 * (size_t)B_ * C_ * E_);  // 32KiB
  float* Dv = (float*)(Wsw + 128 * 128);                // [B][N]
  float* De = Dv + B_ * N_;                             // [B][E]

  k0_prep<<<dim3(16), 256, 0, stream>>>(W, Wsw, De);
  k1_fused<<<dim3(B_ * N_ / 64), 256, 0, stream>>>(H, x, Hbf, xsT, Dv, De);
  gemm1_tr<<<dim3(E_ / 128, 4, B_), 256, 0, stream>>>(Hbf, xsT, P);
  st1_sum4<<<dim3(B_ * C_ * E_ / 8 / 256), 256, 0, stream>>>(P, De, out2T);
  gemm2_fused<<<dim3(N_ / 64, 1, B_), 256, 0, stream>>>(Hbf, out2T, Wsw, bias,
                                                        Dv, out);
}